// Round 5
// baseline (634.518 us; speedup 1.0000x reference)
//
#include <hip/hip_runtime.h>

#define LBL 64
#define TT 1024
#define BB 256
#define BOS 62
#define EOS 63
#define NEGV -10000.0f
#define TCPAD 68   // padded row stride (floats): bank=4(n+g)%32 -> even b128 coverage

__device__ __forceinline__ float rl_f(float v, int l) {
    return __uint_as_float(__builtin_amdgcn_readlane(__float_as_uint(v), l));
}

// ONE WAVE per sentence, ZERO barriers in the time loop.
// lane = next-label n. trans^T lives in LDS (padded rows, ds_read_b128);
// fv broadcast via v_readlane; streaming 4-wide tournament (regs stay low —
// round 2's spill failure mode is avoided by never materializing s[64]).
// Each lane touches only its own tcT row / bp column: no cross-lane LDS deps.
__global__ __launch_bounds__(64, 1) void viterbi_kernel(
    const float* __restrict__ X, const float* __restrict__ trans,
    float* __restrict__ out)
{
    __shared__ float tcT[LBL * TCPAD];        // ~17.4 KiB: tcT[n][p] = trans[p][n]
    __shared__ unsigned char bp[TT][LBL];     // 64 KiB backpointers
    __shared__ unsigned char path_s[TT];      // ~84 KiB total -> 1 block/CU

    const int lane = threadIdx.x;             // next-label n
    const int b    = blockIdx.x;

    // build transposed transition table (lane n writes & later reads row n only)
#pragma unroll 8
    for (int p = 0; p < LBL; ++p)
        tcT[lane * TCPAD + p] = trans[p * LBL + lane];   // coalesced global read

    const float4* rowv = (const float4*)&tcT[lane * TCPAD];  // 272B stride, 16B aligned
    const float*  Xb   = X + (size_t)b * TT * LBL;

    // emission ring, 4 deep (no barriers -> no forced drains; plain dep waits)
    float e0 = Xb[0 * LBL + lane];
    float e1 = Xb[1 * LBL + lane];
    float e2 = Xb[2 * LBL + lane];
    float e3 = Xb[3 * LBL + lane];

    float fvv = (lane == BOS) ? 0.0f : NEGV;

    auto STEP = [&](int t, float e) {
        // 16 groups of 4 prevs: ds_read_b128 (fv-independent, pipelines early)
        float vg[16]; int ig[16];
#pragma unroll
        for (int g = 0; g < 16; ++g) {
            float4 tg = rowv[g];
            float a0 = rl_f(fvv, 4*g+0) + tg.x;
            float a1 = rl_f(fvv, 4*g+1) + tg.y;
            float a2 = rl_f(fvv, 4*g+2) + tg.z;
            float a3 = rl_f(fvv, 4*g+3) + tg.w;
            bool c01 = a1 > a0; float v01 = c01 ? a1 : a0; int i01 = c01 ? 4*g+1 : 4*g+0;
            bool c23 = a3 > a2; float v23 = c23 ? a3 : a2; int i23 = c23 ? 4*g+3 : 4*g+2;
            bool cg  = v23 > v01;
            vg[g] = cg ? v23 : v01;
            ig[g] = cg ? i23 : i01;
        }
        // balanced merge tree (pairs ascending; strict '>' => first-occurrence)
#pragma unroll
        for (int st = 8; st >= 1; st >>= 1)
#pragma unroll
            for (int k = 0; k < st; ++k) {
                bool c = vg[2*k+1] > vg[2*k];
                vg[k] = c ? vg[2*k+1] : vg[2*k];
                ig[k] = c ? ig[2*k+1] : ig[2*k];
            }
        bp[t][lane] = (unsigned char)ig[0];   // fire-and-forget, no drain ever
        fvv = vg[0] + e;                      // exact f32 add == numpy
    };

    for (int t4 = 0; t4 < TT; t4 += 4) {
        // issue next ring quad now (~4 steps ahead >> HBM latency)
        int p0 = t4+4, p1 = t4+5, p2 = t4+6, p3 = t4+7;
        if (p0 > TT-1) p0 = TT-1;  if (p1 > TT-1) p1 = TT-1;
        if (p2 > TT-1) p2 = TT-1;  if (p3 > TT-1) p3 = TT-1;
        float n0 = Xb[(size_t)p0 * LBL + lane];
        float n1 = Xb[(size_t)p1 * LBL + lane];
        float n2 = Xb[(size_t)p2 * LBL + lane];
        float n3 = Xb[(size_t)p3 * LBL + lane];
        STEP(t4+0, e0);
        STEP(t4+1, e1);
        STEP(t4+2, e2);
        STEP(t4+3, e3);
        e0 = n0; e1 = n1; e2 = n2; e3 = n3;
    }

    // ---- termination + wave-wide argmax (butterfly, lower-index-on-tie) ----
    float bv = fvv + trans[lane * LBL + EOS];
    int   bi = lane;
#pragma unroll
    for (int d = 1; d < 64; d <<= 1) {
        float ov = __shfl_xor(bv, d, 64);
        int   oi = __shfl_xor(bi, d, 64);
        if (ov > bv || (ov == bv && oi < bi)) { bv = ov; bi = oi; }
    }
    if (lane == 0) out[b] = bv;

    // ---- backtrack: prefetch bp ROWS (tag-independent), chase via readlane ----
    int stag = bi;   // wave-uniform
    unsigned char r0 = bp[TT-1][lane];
    unsigned char r1 = bp[TT-2][lane];
    unsigned char r2 = bp[TT-3][lane];
    unsigned char r3 = bp[TT-4][lane];
    for (int t4 = TT-1; t4 >= 3; t4 -= 4) {
        int q0 = t4-4, q1 = t4-5, q2 = t4-6, q3 = t4-7;
        if (q0 < 0) q0 = 0;  if (q1 < 0) q1 = 0;
        if (q2 < 0) q2 = 0;  if (q3 < 0) q3 = 0;
        unsigned char m0 = bp[q0][lane];
        unsigned char m1 = bp[q1][lane];
        unsigned char m2 = bp[q2][lane];
        unsigned char m3 = bp[q3][lane];
        // path[t] = tag_t ; tag_{t-1} = bp[t][tag_t]
        if (lane == ((t4-0) & 63)) path_s[t4-0] = (unsigned char)stag;
        stag = __builtin_amdgcn_readlane((int)r0, stag);
        if (lane == ((t4-1) & 63)) path_s[t4-1] = (unsigned char)stag;
        stag = __builtin_amdgcn_readlane((int)r1, stag);
        if (lane == ((t4-2) & 63)) path_s[t4-2] = (unsigned char)stag;
        stag = __builtin_amdgcn_readlane((int)r2, stag);
        if (lane == ((t4-3) & 63)) path_s[t4-3] = (unsigned char)stag;
        stag = __builtin_amdgcn_readlane((int)r3, stag);
        r0 = m0; r1 = m1; r2 = m2; r3 = m3;
    }
    __syncthreads();   // path_s cross-lane visibility (single barrier, once)

    // coalesced float path write
    float* po = out + BB + (size_t)b * TT;
#pragma unroll
    for (int i = 0; i < TT / LBL; ++i)
        po[i * LBL + lane] = (float)path_s[i * LBL + lane];
}

extern "C" void kernel_launch(void* const* d_in, const int* in_sizes, int n_in,
                              void* d_out, int out_size, void* d_ws, size_t ws_size,
                              hipStream_t stream)
{
    const float* X     = (const float*)d_in[0];   // [256, 1024, 64]
    const float* trans = (const float*)d_in[1];   // [64, 64]
    float* out = (float*)d_out;                   // [256] scores ++ [256*1024] path

    viterbi_kernel<<<dim3(BB), dim3(64), 0, stream>>>(X, trans, out);
}

// Round 6
// 618.790 us; speedup vs baseline: 1.0254x; 1.0254x over previous
//
#include <hip/hip_runtime.h>

#define LBL 64
#define TT 1024
#define BB 256
#define BOS 62
#define EOS 63
#define NEGV -10000.0f
#define RS 32          // LDS ring slots (span in flight = 24 < 32)
#define NW (TT / 8)    // 128 eight-step windows

__device__ __forceinline__ float rl_f(float v, int l) {
    return __uint_as_float(__builtin_amdgcn_readlane(__float_as_uint(v), l));
}

// Producer-consumer wave specialization, one sentence per block (4 waves):
//   wave 0: fv recurrence, VALUE-ONLY max (no index tracking) -> fv ring
//   waves 1,2: partial argmax over prev-halves, lag 8 steps (read fv ring)
//   wave 3: combine partials -> bp, lag 16 steps
// One __syncthreads per 8-step window enforces ring visibility; the serial
// critical path (wave 0) carries only 64 rl + 64 add + 63 max per step.
__global__ __launch_bounds__(256, 1) void viterbi_kernel(
    const float* __restrict__ X, const float* __restrict__ trans,
    float* __restrict__ out)
{
    __shared__ float fvring[RS][LBL];          // 8 KiB fv history ring
    __shared__ float pv[2][RS][LBL];           // 16 KiB partial maxima
    __shared__ unsigned int pi[2][RS][LBL];    // 16 KiB partial argmax (global p)
    __shared__ unsigned char bp[TT][LBL];      // 64 KiB backpointers
    __shared__ unsigned char path_s[TT];

    const int tid  = threadIdx.x;
    const int lane = tid & 63;                 // next-label n
    const int wv   = __builtin_amdgcn_readfirstlane(tid >> 6);
    const int b    = blockIdx.x;
    const float* Xb = X + (size_t)b * TT * LBL;

    float fvv = (lane == BOS) ? 0.0f : NEGV;   // fv_{-1} (only wave 0's is live)

    if (wv == 0) {
        // ---------------- producer: value-only fv recurrence ----------------
        float tc[LBL];
#pragma unroll
        for (int p = 0; p < LBL; ++p) tc[p] = trans[p * LBL + lane];
        fvring[0][lane] = fvv;                 // fv_{-1} -> slot 0

        float eA[8], eB[8];
#pragma unroll
        for (int j = 0; j < 8; ++j) eA[j] = Xb[j * LBL + lane];

        auto DOW = [&](float (&cons)[8], float (&nxt)[8], int W) {
            // issue NEXT window's emissions now (returns long before next drain)
#pragma unroll
            for (int j = 0; j < 8; ++j) {
                int st = 8 * (W + 1) + j; if (st > TT - 1) st = TT - 1;
                nxt[j] = Xb[(size_t)st * LBL + lane];
            }
#pragma unroll
            for (int j = 0; j < 8; ++j) {
                // balanced value-max tree, depth 6 (chain ~24 cyc, issue-bound)
                float mm[16];
#pragma unroll
                for (int g = 0; g < 16; ++g) {
                    float a0 = rl_f(fvv, 4*g+0) + tc[4*g+0];
                    float a1 = rl_f(fvv, 4*g+1) + tc[4*g+1];
                    float a2 = rl_f(fvv, 4*g+2) + tc[4*g+2];
                    float a3 = rl_f(fvv, 4*g+3) + tc[4*g+3];
                    mm[g] = fmaxf(fmaxf(a0, a1), fmaxf(a2, a3));
                }
#pragma unroll
                for (int st = 8; st >= 1; st >>= 1)
#pragma unroll
                    for (int k = 0; k < st; ++k)
                        mm[k] = fmaxf(mm[2*k], mm[2*k+1]);
                fvv = mm[0] + cons[j];                       // exact f32 adds
                fvring[(8*W + j + 1) & (RS-1)][lane] = fvv;  // publish fv_t
            }
        };

        for (int W = 0; W < NW + 2; ++W) {
            __syncthreads();
            if (W < NW) {
                if ((W & 1) == 0) DOW(eA, eB, W);
                else              DOW(eB, eA, W);
            }
        }
    } else if (wv <= 2) {
        // ------------- consumers: partial argmax over 32 prevs, lag 8 -------------
        const int pbase = (wv - 1) * 32;
        const int ww    = wv - 1;
        float tcr[32];
#pragma unroll
        for (int i = 0; i < 32; ++i) tcr[i] = trans[(pbase + i) * LBL + lane];

        for (int W = 0; W < NW + 2; ++W) {
            __syncthreads();
            if (W >= 1 && W <= NW) {
                const int tb = 8 * (W - 1);
#pragma unroll
                for (int j = 0; j < 8; ++j) {
                    const int t = tb + j, slot = t & (RS - 1);
                    // fv_{t-1} row: broadcast b128 reads (same addr all lanes)
                    const float4* fr = (const float4*)&fvring[slot][pbase];
                    float vgv[8]; int vgi[8];
#pragma unroll
                    for (int g = 0; g < 8; ++g) {
                        float4 f = fr[g];
                        float a0 = f.x + tcr[4*g+0];
                        float a1 = f.y + tcr[4*g+1];
                        float a2 = f.z + tcr[4*g+2];
                        float a3 = f.w + tcr[4*g+3];
                        // strict '>' + ascending p = first-occurrence (np.argmax)
                        bool c01 = a1 > a0; float v01 = c01 ? a1 : a0;
                        int  i01 = pbase + 4*g + (c01 ? 1 : 0);
                        bool c23 = a3 > a2; float v23 = c23 ? a3 : a2;
                        int  i23 = pbase + 4*g + 2 + (c23 ? 1 : 0);
                        bool cg  = v23 > v01;
                        vgv[g] = cg ? v23 : v01;
                        vgi[g] = cg ? i23 : i01;
                    }
#pragma unroll
                    for (int st = 4; st >= 1; st >>= 1)
#pragma unroll
                        for (int k = 0; k < st; ++k) {
                            bool c = vgv[2*k+1] > vgv[2*k];
                            vgv[k] = c ? vgv[2*k+1] : vgv[2*k];
                            vgi[k] = c ? vgi[2*k+1] : vgi[2*k];
                        }
                    pv[ww][slot][lane] = vgv[0];
                    pi[ww][slot][lane] = (unsigned)vgi[0];
                }
            }
        }
    } else {
        // ------------- combiner: merge halves -> bp, lag 16 -------------
        for (int W = 0; W < NW + 2; ++W) {
            __syncthreads();
            if (W >= 2) {
                const int tb = 8 * (W - 2);
#pragma unroll
                for (int j = 0; j < 8; ++j) {
                    const int t = tb + j, slot = t & (RS - 1);
                    float    v1 = pv[0][slot][lane];
                    float    v2 = pv[1][slot][lane];
                    unsigned i1 = pi[0][slot][lane];
                    unsigned i2 = pi[1][slot][lane];
                    // lower half wins ties (strict '>') = first-occurrence
                    bp[t][lane] = (unsigned char)((v2 > v1) ? i2 : i1);
                }
            }
        }
    }

    __syncthreads();   // final combines (window NW+1) visible to wave 0

    // ---- termination + backtrack (wave 0; r5-validated readlane chase) ----
    if (wv == 0) {
        float bv = fvv + trans[lane * LBL + EOS];
        int   bi = lane;
#pragma unroll
        for (int d = 1; d < 64; d <<= 1) {
            float ov = __shfl_xor(bv, d, 64);
            int   oi = __shfl_xor(bi, d, 64);
            if (ov > bv || (ov == bv && oi < bi)) { bv = ov; bi = oi; }
        }
        if (lane == 0) out[b] = bv;

        int stag = bi;   // wave-uniform
        unsigned char r0 = bp[TT-1][lane];
        unsigned char r1 = bp[TT-2][lane];
        unsigned char r2 = bp[TT-3][lane];
        unsigned char r3 = bp[TT-4][lane];
        for (int t4 = TT - 1; t4 >= 3; t4 -= 4) {
            int q0 = t4-4, q1 = t4-5, q2 = t4-6, q3 = t4-7;
            if (q0 < 0) q0 = 0;  if (q1 < 0) q1 = 0;
            if (q2 < 0) q2 = 0;  if (q3 < 0) q3 = 0;
            unsigned char m0 = bp[q0][lane];
            unsigned char m1 = bp[q1][lane];
            unsigned char m2 = bp[q2][lane];
            unsigned char m3 = bp[q3][lane];
            if (lane == ((t4-0) & 63)) path_s[t4-0] = (unsigned char)stag;
            stag = __builtin_amdgcn_readlane((int)r0, stag);
            if (lane == ((t4-1) & 63)) path_s[t4-1] = (unsigned char)stag;
            stag = __builtin_amdgcn_readlane((int)r1, stag);
            if (lane == ((t4-2) & 63)) path_s[t4-2] = (unsigned char)stag;
            stag = __builtin_amdgcn_readlane((int)r2, stag);
            if (lane == ((t4-3) & 63)) path_s[t4-3] = (unsigned char)stag;
            stag = __builtin_amdgcn_readlane((int)r3, stag);
            r0 = m0; r1 = m1; r2 = m2; r3 = m3;
        }
    }
    __syncthreads();

    // coalesced float path write (all 256 threads)
    float* po = out + BB + (size_t)b * TT;
#pragma unroll
    for (int i = 0; i < TT / 256; ++i)
        po[i * 256 + tid] = (float)path_s[i * 256 + tid];
}

extern "C" void kernel_launch(void* const* d_in, const int* in_sizes, int n_in,
                              void* d_out, int out_size, void* d_ws, size_t ws_size,
                              hipStream_t stream)
{
    const float* X     = (const float*)d_in[0];   // [256, 1024, 64]
    const float* trans = (const float*)d_in[1];   // [64, 64]
    float* out = (float*)d_out;                   // [256] scores ++ [256*1024] path

    viterbi_kernel<<<dim3(BB), dim3(256), 0, stream>>>(X, trans, out);
}